// Round 12
// baseline (134.226 us; speedup 1.0000x reference)
//
#include <hip/hip_runtime.h>
#include <math.h>

#define NC    10
#define BATCH 256
#define IC    1152
#define LDIM  8
#define OC    16

#define NCH   96
#define CH    (IC/NCH)        // 12 i's per block
#define NPAIR 5               // n-pairs per chunk
#define NBLK  (NCH*NPAIR)     // 480 blocks (60 per XCD exactly)
#define NTHR  256
#define NTOT  (NC*BATCH*OC)   // 40960
#define NRED  160             // kR blocks / n2 partials
#define KPG   (NCH/4)         // 24 chunks per wave-group in kR

typedef float f32x2 __attribute__((ext_vector_type(2)));

// ch-major XCD decode: XCD k owns ch in [12k,12k+12) for ALL n-pairs ->
// per-XCD xT window 1.15 MB + w window 0.74 MB, both L2-resident.
__device__ __forceinline__ void decode(int bid, int& ch, int& n0) {
    int xcd = bid & 7, q = bid >> 3;      // q in [0,60)
    ch = xcd * 12 + (q % 12);
    n0 = (q / 12) * 2;                    // n-pair {n0, n0+1}
}

// ---------------------------------------------------------------------------
// K0: transpose x[b][i][l] -> xT[i][b][l]
// ---------------------------------------------------------------------------
__global__ __launch_bounds__(256) void k0_xT(const float* __restrict__ x,
                                             float* __restrict__ xT)
{
    int u = blockIdx.x * 256 + threadIdx.x;       // < 589824
    int i = u >> 9, r = u & 511, b = r >> 1, h = r & 1;
    reinterpret_cast<float4*>(xT)[u] =
        reinterpret_cast<const float4*>(x)[((size_t)b * IC + i) * 2 + h];
}

// ---------------------------------------------------------------------------
// KA: iter-0 s partials (c uniform = 1/256). thread = b, TWO n's per block:
// xT loaded once, used for both n.
// ---------------------------------------------------------------------------
__global__ __launch_bounds__(256) void kA(
    const float* __restrict__ xT, const float* __restrict__ w,
    float* __restrict__ s_part)
{
    int ch, n0; decode(blockIdx.x, ch, n0);
    int i0 = ch * CH;
    int t  = threadIdx.x;            // = b

    f32x2 spA[8], spB[8];
#pragma unroll
    for (int j = 0; j < 8; ++j) { spA[j] = (f32x2){0.f,0.f}; spB[j] = (f32x2){0.f,0.f}; }

    for (int ii = 0; ii < CH; ++ii) {
        int i = i0 + ii;
        const float4* xp = reinterpret_cast<const float4*>(xT)
                         + ((size_t)i * BATCH + t) * 2;
        float4 xa = xp[0], xb = xp[1];
        float xr[8] = {xa.x, xa.y, xa.z, xa.w, xb.x, xb.y, xb.z, xb.w};
        const f32x2* w0 = reinterpret_cast<const f32x2*>(
            w + (size_t)__builtin_amdgcn_readfirstlane((n0 * IC + i) * (LDIM * OC)));
        const f32x2* w1 = reinterpret_cast<const f32x2*>(
            w + (size_t)__builtin_amdgcn_readfirstlane(((n0+1) * IC + i) * (LDIM * OC)));
#pragma unroll
        for (int l = 0; l < LDIM; ++l) {
            f32x2 xl = {xr[l], xr[l]};
#pragma unroll
            for (int j = 0; j < 8; ++j) {
                spA[j] += w0[l * 8 + j] * xl;
                spB[j] += w1[l * 8 + j] * xl;
            }
        }
    }
    const float inv = 1.0f / 256.0f;
    float4* dA = reinterpret_cast<float4*>(s_part)
               + (((size_t)ch * NC + n0) * BATCH + t) * 4;
    float4* dB = reinterpret_cast<float4*>(s_part)
               + (((size_t)ch * NC + n0 + 1) * BATCH + t) * 4;
#pragma unroll
    for (int j = 0; j < 4; ++j) {
        dA[j] = make_float4(spA[2*j].x*inv, spA[2*j].y*inv, spA[2*j+1].x*inv, spA[2*j+1].y*inv);
        dB[j] = make_float4(spB[2*j].x*inv, spB[2*j].y*inv, spB[2*j+1].x*inv, spB[2*j+1].y*inv);
    }
}

// ---------------------------------------------------------------------------
// KR: 160 blocks. Wave g sums chunks [g*24, g*24+24) as float4 with FOUR
// independent accumulators (fixed tree -> deterministic); LDS combine.
// ---------------------------------------------------------------------------
__global__ __launch_bounds__(256) void kR(const float* __restrict__ s_part,
                                          float* __restrict__ s,
                                          float* __restrict__ n2_part)
{
    __shared__ float4 lds[4][64];
    int t = threadIdx.x, lane = t & 63, g = t >> 6;
    int idx0 = blockIdx.x * 256;
    const float* base = s_part + idx0 + lane * 4;
    float4 a0 = make_float4(0,0,0,0), a1 = a0, a2 = a0, a3 = a0;
    for (int k = 0; k < KPG; k += 4) {
        float4 v0 = *reinterpret_cast<const float4*>(base + (size_t)(g*KPG + k    ) * NTOT);
        float4 v1 = *reinterpret_cast<const float4*>(base + (size_t)(g*KPG + k + 1) * NTOT);
        float4 v2 = *reinterpret_cast<const float4*>(base + (size_t)(g*KPG + k + 2) * NTOT);
        float4 v3 = *reinterpret_cast<const float4*>(base + (size_t)(g*KPG + k + 3) * NTOT);
        a0.x += v0.x; a0.y += v0.y; a0.z += v0.z; a0.w += v0.w;
        a1.x += v1.x; a1.y += v1.y; a1.z += v1.z; a1.w += v1.w;
        a2.x += v2.x; a2.y += v2.y; a2.z += v2.z; a2.w += v2.w;
        a3.x += v3.x; a3.y += v3.y; a3.z += v3.z; a3.w += v3.w;
    }
    float4 a = make_float4((a0.x+a1.x)+(a2.x+a3.x), (a0.y+a1.y)+(a2.y+a3.y),
                           (a0.z+a1.z)+(a2.z+a3.z), (a0.w+a1.w)+(a2.w+a3.w));
    lds[g][lane] = a;
    __syncthreads();
    if (t < 64) {
        float4 s0 = lds[0][t], s1 = lds[1][t], s2 = lds[2][t], s3 = lds[3][t];
        float4 sv = make_float4((s0.x+s1.x)+(s2.x+s3.x), (s0.y+s1.y)+(s2.y+s3.y),
                                (s0.z+s1.z)+(s2.z+s3.z), (s0.w+s1.w)+(s2.w+s3.w));
        *reinterpret_cast<float4*>(s + idx0 + t * 4) = sv;
        float q = sv.x*sv.x + sv.y*sv.y + sv.z*sv.z + sv.w*sv.w;
#pragma unroll
        for (int m = 32; m >= 1; m >>= 1) q += __shfl_xor(q, m, 64);
        if (t == 0) n2_part[blockIdx.x] = q;
    }
}

// ---------------------------------------------------------------------------
// KB: fused routing step, TWO n's per block (xT loaded once, shared barrier,
// ILP-2 softmax chains). Per i: p = priors, beta = p.v (+old betaT),
// in-block softmax over b -> c, sp += c*p.
// ---------------------------------------------------------------------------
template<bool FIRST>
__global__ __launch_bounds__(256) void kB(
    const float* __restrict__ xT, const float* __restrict__ w,
    const float* __restrict__ s, const float* __restrict__ n2_part,
    float* __restrict__ betaT, float* __restrict__ s_part)
{
    __shared__ float redA[2][2][4];     // [ii parity][nn][wave]
    __shared__ float redW[4];
    int t = threadIdx.x, lane = t & 63, wid = t >> 6;
    int ch, n0; decode(blockIdx.x, ch, n0);
    int i0 = ch * CH;

    // squash scale (redundant per block, fixed order)
    float q = (t < NRED) ? n2_part[t] : 0.f;
#pragma unroll
    for (int m = 32; m >= 1; m >>= 1) q += __shfl_xor(q, m, 64);
    if (lane == 0) redW[wid] = q;
    __syncthreads();
    float n2 = (redW[0] + redW[1]) + (redW[2] + redW[3]);
    float sc = sqrtf(n2) / (1.0f + n2);

    // v for both n's (packed)
    f32x2 vA[8], vB[8];
    {
        f32x2 scv = {sc, sc};
        const f32x2* sA = reinterpret_cast<const f32x2*>(s)
                        + ((size_t)n0 * BATCH + t) * 8;
        const f32x2* sB = reinterpret_cast<const f32x2*>(s)
                        + ((size_t)(n0+1) * BATCH + t) * 8;
#pragma unroll
        for (int j = 0; j < 8; ++j) { vA[j] = sA[j] * scv; vB[j] = sB[j] * scv; }
    }

    f32x2 spA[8], spB[8];
#pragma unroll
    for (int j = 0; j < 8; ++j) { spA[j] = (f32x2){0.f,0.f}; spB[j] = (f32x2){0.f,0.f}; }

    for (int ii = 0; ii < CH; ++ii) {
        int i = i0 + ii;
        const float4* xp = reinterpret_cast<const float4*>(xT)
                         + ((size_t)i * BATCH + t) * 2;
        float4 xa = xp[0], xb = xp[1];
        float xr[8] = {xa.x, xa.y, xa.z, xa.w, xb.x, xb.y, xb.z, xb.w};
        const f32x2* w0 = reinterpret_cast<const f32x2*>(
            w + (size_t)__builtin_amdgcn_readfirstlane((n0 * IC + i) * (LDIM * OC)));
        const f32x2* w1 = reinterpret_cast<const f32x2*>(
            w + (size_t)__builtin_amdgcn_readfirstlane(((n0+1) * IC + i) * (LDIM * OC)));

        f32x2 pA[8], pB[8];
#pragma unroll
        for (int j = 0; j < 8; ++j) { pA[j] = (f32x2){0.f,0.f}; pB[j] = (f32x2){0.f,0.f}; }
#pragma unroll
        for (int l = 0; l < LDIM; ++l) {
            f32x2 xl = {xr[l], xr[l]};
#pragma unroll
            for (int j = 0; j < 8; ++j) {
                pA[j] += w0[l * 8 + j] * xl;
                pB[j] += w1[l * 8 + j] * xl;
            }
        }

        f32x2 dA = pA[0] * vA[0], dB = pB[0] * vB[0];
#pragma unroll
        for (int j = 1; j < 8; ++j) { dA += pA[j] * vA[j]; dB += pB[j] * vB[j]; }
        float dotA = dA.x + dA.y, dotB = dB.x + dB.y;

        size_t biA = ((size_t)n0 * IC + i) * BATCH + t;       // coalesced
        size_t biB = ((size_t)(n0+1) * IC + i) * BATCH + t;
        float betaA, betaB;
        if (FIRST) { betaA = dotA; betaT[biA] = betaA;
                     betaB = dotB; betaT[biB] = betaB; }
        else       { betaA = betaT[biA] + dotA;
                     betaB = betaT[biB] + dotB; }

        // in-block softmax over b, two independent chains (ILP-2)
        float eA = __expf(betaA), eB = __expf(betaB);
        float esA = eA, esB = eB;
#pragma unroll
        for (int m = 1; m < 64; m <<= 1) {
            esA += __shfl_xor(esA, m, 64);
            esB += __shfl_xor(esB, m, 64);
        }
        if (lane == 0) { redA[ii & 1][0][wid] = esA; redA[ii & 1][1][wid] = esB; }
        __syncthreads();
        float denA = (redA[ii&1][0][0] + redA[ii&1][0][1])
                   + (redA[ii&1][0][2] + redA[ii&1][0][3]);
        float denB = (redA[ii&1][1][0] + redA[ii&1][1][1])
                   + (redA[ii&1][1][2] + redA[ii&1][1][3]);
        f32x2 cA = {eA / denA, eA / denA};
        f32x2 cB = {eB / denB, eB / denB};
#pragma unroll
        for (int j = 0; j < 8; ++j) { spA[j] += cA * pA[j]; spB[j] += cB * pB[j]; }
    }

    float4* dA = reinterpret_cast<float4*>(s_part)
               + (((size_t)ch * NC + n0) * BATCH + t) * 4;
    float4* dB = reinterpret_cast<float4*>(s_part)
               + (((size_t)ch * NC + n0 + 1) * BATCH + t) * 4;
#pragma unroll
    for (int j = 0; j < 4; ++j) {
        dA[j] = make_float4(spA[2*j].x, spA[2*j].y, spA[2*j+1].x, spA[2*j+1].y);
        dB[j] = make_float4(spB[2*j].x, spB[2*j].y, spB[2*j+1].x, spB[2*j+1].y);
    }
}

// ---------------------------------------------------------------------------
// K_OUT: n2 from partials; out = s * scale
// ---------------------------------------------------------------------------
__global__ __launch_bounds__(256) void k_out(const float* __restrict__ s,
                                             const float* __restrict__ n2_part,
                                             float* __restrict__ out)
{
    __shared__ float redW[4];
    int t = threadIdx.x, lane = t & 63, wid = t >> 6;
    float q = (t < NRED) ? n2_part[t] : 0.f;
#pragma unroll
    for (int m = 32; m >= 1; m >>= 1) q += __shfl_xor(q, m, 64);
    if (lane == 0) redW[wid] = q;
    __syncthreads();
    float n2 = (redW[0] + redW[1]) + (redW[2] + redW[3]);
    float sc = sqrtf(n2) / (1.0f + n2);
    int idx = blockIdx.x * 256 + t;
    out[idx] = s[idx] * sc;
}

// ---------------------------------------------------------------------------
extern "C" void kernel_launch(void* const* d_in, const int* in_sizes, int n_in,
                              void* d_out, int out_size, void* d_ws, size_t ws_size,
                              hipStream_t stream)
{
    const float* x = (const float*)d_in[0];   // [256,1152,8]
    const float* w = (const float*)d_in[1];   // [10,1152,8,16]
    float* out = (float*)d_out;               // 40960 floats
    float* ws  = (float*)d_ws;

    float* xT      = ws;                                  // 2,359,296
    float* betaT   = xT + (size_t)IC * BATCH * LDIM;      // 2,949,120
    float* s       = betaT + (size_t)NC * IC * BATCH;     //    40,960
    float* s_part  = s + NTOT;                            // 3,932,160
    float* n2_part = s_part + (size_t)NCH * NTOT;         //       160
    // total ~37 MB of workspace

    dim3 blk(256);

    k0_xT<<<2304, blk, 0, stream>>>(x, xT);
    // iter 1: c uniform
    kA<<<NBLK, blk, 0, stream>>>(xT, w, s_part);
    kR<<<NRED, blk, 0, stream>>>(s_part, s, n2_part);
    // iter 2: beta1 = p.v0, softmax, s1
    kB<true><<<NBLK, blk, 0, stream>>>(xT, w, s, n2_part, betaT, s_part);
    kR<<<NRED, blk, 0, stream>>>(s_part, s, n2_part);
    // iter 3: beta2 = beta1 + p.v1, softmax, s2
    kB<false><<<NBLK, blk, 0, stream>>>(xT, w, s, n2_part, betaT, s_part);
    kR<<<NRED, blk, 0, stream>>>(s_part, s, n2_part);
    // final squash -> out
    k_out<<<NRED, blk, 0, stream>>>(s, n2_part, out);
}

// Round 13
// 94.978 us; speedup vs baseline: 1.4132x; 1.4132x over previous
//
#include <hip/hip_runtime.h>
#include <math.h>

#define NC    10
#define BATCH 256
#define IC    1152
#define LDIM  8
#define OC    16

#define NCH   96
#define CH    (IC/NCH)        // 12 i's per block
#define NBLK  (NC*NCH)        // 960 blocks
#define NTHR  256
#define NTOT  (NC*BATCH*OC)   // 40960
#define NRED  160             // kR blocks / n2 partials
#define KPG   (NCH/4)         // 24 chunks per wave-group in kR

typedef float f32x2 __attribute__((ext_vector_type(2)));

// R8 n-major swizzle (best measured config)
__device__ __forceinline__ int xcd_swizzle(int bid, int nwg) {
    int cpx = nwg >> 3;
    return (bid & 7) * cpx + (bid >> 3);
}

// ---------------------------------------------------------------------------
// K0: transpose x[b][i][l] -> xT[i][b][l]
// ---------------------------------------------------------------------------
__global__ __launch_bounds__(256) void k0_xT(const float* __restrict__ x,
                                             float* __restrict__ xT)
{
    int u = blockIdx.x * 256 + threadIdx.x;       // < 589824
    int i = u >> 9, r = u & 511, b = r >> 1, h = r & 1;
    reinterpret_cast<float4*>(xT)[u] =
        reinterpret_cast<const float4*>(x)[((size_t)b * IC + i) * 2 + h];
}

// ---------------------------------------------------------------------------
// KA: iter-0 s partials (c uniform = 1/256). thread = b. (R8 version)
// ---------------------------------------------------------------------------
__global__ __launch_bounds__(256) void kA(
    const float* __restrict__ xT, const float* __restrict__ w,
    float* __restrict__ s_part)
{
    int wg = xcd_swizzle(blockIdx.x, NBLK);
    int n  = wg / NCH, ch = wg % NCH;
    int i0 = ch * CH;
    int t  = threadIdx.x;            // = b

    f32x2 sp2[8];
#pragma unroll
    for (int j = 0; j < 8; ++j) sp2[j] = (f32x2){0.f, 0.f};

    for (int ii = 0; ii < CH; ++ii) {
        int i = i0 + ii;
        const float4* xp = reinterpret_cast<const float4*>(xT)
                         + ((size_t)i * BATCH + t) * 2;
        float4 xa = xp[0], xb = xp[1];
        float xr[8] = {xa.x, xa.y, xa.z, xa.w, xb.x, xb.y, xb.z, xb.w};
        const f32x2* wp2 = reinterpret_cast<const f32x2*>(
            w + (size_t)__builtin_amdgcn_readfirstlane((n * IC + i) * (LDIM * OC)));
#pragma unroll
        for (int l = 0; l < LDIM; ++l) {
            f32x2 xl = {xr[l], xr[l]};
#pragma unroll
            for (int j = 0; j < 8; ++j)
                sp2[j] += wp2[l * 8 + j] * xl;    // v_pk_fma_f32
        }
    }
    float4* dst = reinterpret_cast<float4*>(s_part)
                + (((size_t)ch * NC + n) * BATCH + t) * 4;
    const float inv = 1.0f / 256.0f;
    dst[0] = make_float4(sp2[0].x*inv, sp2[0].y*inv, sp2[1].x*inv, sp2[1].y*inv);
    dst[1] = make_float4(sp2[2].x*inv, sp2[2].y*inv, sp2[3].x*inv, sp2[3].y*inv);
    dst[2] = make_float4(sp2[4].x*inv, sp2[4].y*inv, sp2[5].x*inv, sp2[5].y*inv);
    dst[3] = make_float4(sp2[6].x*inv, sp2[6].y*inv, sp2[7].x*inv, sp2[7].y*inv);
}

// ---------------------------------------------------------------------------
// KR: 160 blocks. Wave g sums chunks [g*24, g*24+24) as float4 with FOUR
// independent accumulators (fixed tree -> deterministic, ILP-4); LDS combine.
// ---------------------------------------------------------------------------
__global__ __launch_bounds__(256) void kR(const float* __restrict__ s_part,
                                          float* __restrict__ s,
                                          float* __restrict__ n2_part)
{
    __shared__ float4 lds[4][64];
    int t = threadIdx.x, lane = t & 63, g = t >> 6;
    int idx0 = blockIdx.x * 256;
    const float* base = s_part + idx0 + lane * 4;
    float4 a0 = make_float4(0,0,0,0), a1 = a0, a2 = a0, a3 = a0;
    for (int k = 0; k < KPG; k += 4) {
        float4 v0 = *reinterpret_cast<const float4*>(base + (size_t)(g*KPG + k    ) * NTOT);
        float4 v1 = *reinterpret_cast<const float4*>(base + (size_t)(g*KPG + k + 1) * NTOT);
        float4 v2 = *reinterpret_cast<const float4*>(base + (size_t)(g*KPG + k + 2) * NTOT);
        float4 v3 = *reinterpret_cast<const float4*>(base + (size_t)(g*KPG + k + 3) * NTOT);
        a0.x += v0.x; a0.y += v0.y; a0.z += v0.z; a0.w += v0.w;
        a1.x += v1.x; a1.y += v1.y; a1.z += v1.z; a1.w += v1.w;
        a2.x += v2.x; a2.y += v2.y; a2.z += v2.z; a2.w += v2.w;
        a3.x += v3.x; a3.y += v3.y; a3.z += v3.z; a3.w += v3.w;
    }
    float4 a = make_float4((a0.x+a1.x)+(a2.x+a3.x), (a0.y+a1.y)+(a2.y+a3.y),
                           (a0.z+a1.z)+(a2.z+a3.z), (a0.w+a1.w)+(a2.w+a3.w));
    lds[g][lane] = a;
    __syncthreads();
    if (t < 64) {
        float4 s0 = lds[0][t], s1 = lds[1][t], s2 = lds[2][t], s3 = lds[3][t];
        float4 sv = make_float4((s0.x+s1.x)+(s2.x+s3.x), (s0.y+s1.y)+(s2.y+s3.y),
                                (s0.z+s1.z)+(s2.z+s3.z), (s0.w+s1.w)+(s2.w+s3.w));
        *reinterpret_cast<float4*>(s + idx0 + t * 4) = sv;
        float q = sv.x*sv.x + sv.y*sv.y + sv.z*sv.z + sv.w*sv.w;
#pragma unroll
        for (int m = 32; m >= 1; m >>= 1) q += __shfl_xor(q, m, 64);
        if (t == 0) n2_part[blockIdx.x] = q;
    }
}

// ---------------------------------------------------------------------------
// KB: fused routing step, ii-PAIRED: two i's per inner step -> ILP-2 softmax
// chains, HALF the barriers (6 not 12), merged w s-load region.
// Per i: p = priors(:,i), beta = p.v (+old betaT), in-block softmax over b,
// sp += c*p. Parity double-buffered LDS partials (race-safe, one barrier/pair).
// ---------------------------------------------------------------------------
template<bool FIRST>
__global__ __launch_bounds__(256) void kB(
    const float* __restrict__ xT, const float* __restrict__ w,
    const float* __restrict__ s, const float* __restrict__ n2_part,
    float* __restrict__ betaT, float* __restrict__ s_part)
{
    __shared__ float redA[2][2][4];   // [pair parity][i-slot][wave]
    __shared__ float redW[4];
    int t = threadIdx.x, lane = t & 63, wid = t >> 6;
    int wg = xcd_swizzle(blockIdx.x, NBLK);
    int n  = wg / NCH, ch = wg % NCH;
    int i0 = ch * CH;

    // squash scale (redundant per block, fixed order)
    float q = (t < NRED) ? n2_part[t] : 0.f;
#pragma unroll
    for (int m = 32; m >= 1; m >>= 1) q += __shfl_xor(q, m, 64);
    if (lane == 0) redW[wid] = q;
    __syncthreads();
    float n2 = (redW[0] + redW[1]) + (redW[2] + redW[3]);
    float sc = sqrtf(n2) / (1.0f + n2);

    // v[n,b,:] = s * scale (packed)
    f32x2 v2[8];
    {
        const f32x2* svp = reinterpret_cast<const f32x2*>(s)
                         + ((size_t)n * BATCH + t) * 8;
        f32x2 scv = {sc, sc};
#pragma unroll
        for (int j = 0; j < 8; ++j) v2[j] = svp[j] * scv;
    }

    f32x2 sp2[8];
#pragma unroll
    for (int j = 0; j < 8; ++j) sp2[j] = (f32x2){0.f, 0.f};

    for (int pr = 0; pr < CH / 2; ++pr) {
        int i = i0 + 2 * pr;        // pair {i, i+1}
        const float4* xp = reinterpret_cast<const float4*>(xT)
                         + ((size_t)i * BATCH + t) * 2;
        float4 xa0 = xp[0], xb0 = xp[1];
        float4 xa1 = xp[2 * BATCH], xb1 = xp[2 * BATCH + 1];
        float xr0[8] = {xa0.x, xa0.y, xa0.z, xa0.w, xb0.x, xb0.y, xb0.z, xb0.w};
        float xr1[8] = {xa1.x, xa1.y, xa1.z, xa1.w, xb1.x, xb1.y, xb1.z, xb1.w};
        const f32x2* wp2 = reinterpret_cast<const f32x2*>(
            w + (size_t)__builtin_amdgcn_readfirstlane((n * IC + i) * (LDIM * OC)));

        f32x2 pA[8], pB[8];
#pragma unroll
        for (int j = 0; j < 8; ++j) { pA[j] = (f32x2){0.f,0.f}; pB[j] = (f32x2){0.f,0.f}; }
#pragma unroll
        for (int l = 0; l < LDIM; ++l) {
            f32x2 x0 = {xr0[l], xr0[l]}, x1 = {xr1[l], xr1[l]};
#pragma unroll
            for (int j = 0; j < 8; ++j) {
                pA[j] += wp2[l * 8 + j] * x0;            // i
                pB[j] += wp2[64 + l * 8 + j] * x1;       // i+1 (adjacent w row)
            }
        }

        f32x2 dA = pA[0] * v2[0], dB = pB[0] * v2[0];
#pragma unroll
        for (int j = 1; j < 8; ++j) { dA += pA[j] * v2[j]; dB += pB[j] * v2[j]; }
        float dotA = dA.x + dA.y, dotB = dB.x + dB.y;

        size_t biA = ((size_t)n * IC + i) * BATCH + t;   // coalesced
        size_t biB = biA + BATCH;
        float betaA, betaB;
        if (FIRST) { betaA = dotA; betaT[biA] = betaA;
                     betaB = dotB; betaT[biB] = betaB; }
        else       { betaA = betaT[biA] + dotA;
                     betaB = betaT[biB] + dotB; }

        // in-block softmax over b: two independent chains, ILP-2, ONE barrier
        float eA = __expf(betaA), eB = __expf(betaB);
        float esA = eA, esB = eB;
#pragma unroll
        for (int m = 1; m < 64; m <<= 1) {
            esA += __shfl_xor(esA, m, 64);
            esB += __shfl_xor(esB, m, 64);
        }
        if (lane == 0) { redA[pr & 1][0][wid] = esA; redA[pr & 1][1][wid] = esB; }
        __syncthreads();
        float denA = (redA[pr&1][0][0] + redA[pr&1][0][1])
                   + (redA[pr&1][0][2] + redA[pr&1][0][3]);
        float denB = (redA[pr&1][1][0] + redA[pr&1][1][1])
                   + (redA[pr&1][1][2] + redA[pr&1][1][3]);
        float cA = eA / denA, cB = eB / denB;
        f32x2 cA2 = {cA, cA}, cB2 = {cB, cB};
#pragma unroll
        for (int j = 0; j < 8; ++j) sp2[j] += cA2 * pA[j] + cB2 * pB[j];
    }

    float4* dst = reinterpret_cast<float4*>(s_part)
                + (((size_t)ch * NC + n) * BATCH + t) * 4;
    dst[0] = make_float4(sp2[0].x, sp2[0].y, sp2[1].x, sp2[1].y);
    dst[1] = make_float4(sp2[2].x, sp2[2].y, sp2[3].x, sp2[3].y);
    dst[2] = make_float4(sp2[4].x, sp2[4].y, sp2[5].x, sp2[5].y);
    dst[3] = make_float4(sp2[6].x, sp2[6].y, sp2[7].x, sp2[7].y);
}

// ---------------------------------------------------------------------------
// K_OUT: n2 from partials; out = s * scale
// ---------------------------------------------------------------------------
__global__ __launch_bounds__(256) void k_out(const float* __restrict__ s,
                                             const float* __restrict__ n2_part,
                                             float* __restrict__ out)
{
    __shared__ float redW[4];
    int t = threadIdx.x, lane = t & 63, wid = t >> 6;
    float q = (t < NRED) ? n2_part[t] : 0.f;
#pragma unroll
    for (int m = 32; m >= 1; m >>= 1) q += __shfl_xor(q, m, 64);
    if (lane == 0) redW[wid] = q;
    __syncthreads();
    float n2 = (redW[0] + redW[1]) + (redW[2] + redW[3]);
    float sc = sqrtf(n2) / (1.0f + n2);
    int idx = blockIdx.x * 256 + t;
    out[idx] = s[idx] * sc;
}

// ---------------------------------------------------------------------------
extern "C" void kernel_launch(void* const* d_in, const int* in_sizes, int n_in,
                              void* d_out, int out_size, void* d_ws, size_t ws_size,
                              hipStream_t stream)
{
    const float* x = (const float*)d_in[0];   // [256,1152,8]
    const float* w = (const float*)d_in[1];   // [10,1152,8,16]
    float* out = (float*)d_out;               // 40960 floats
    float* ws  = (float*)d_ws;

    float* xT      = ws;                                  // 2,359,296
    float* betaT   = xT + (size_t)IC * BATCH * LDIM;      // 2,949,120
    float* s       = betaT + (size_t)NC * IC * BATCH;     //    40,960
    float* s_part  = s + NTOT;                            // 3,932,160
    float* n2_part = s_part + (size_t)NCH * NTOT;         //       160
    // total ~37 MB of workspace

    dim3 blk(256);

    k0_xT<<<2304, blk, 0, stream>>>(x, xT);
    // iter 1: c uniform
    kA<<<NBLK, blk, 0, stream>>>(xT, w, s_part);
    kR<<<NRED, blk, 0, stream>>>(s_part, s, n2_part);
    // iter 2: beta1 = p.v0, softmax, s1
    kB<true><<<NBLK, blk, 0, stream>>>(xT, w, s, n2_part, betaT, s_part);
    kR<<<NRED, blk, 0, stream>>>(s_part, s, n2_part);
    // iter 3: beta2 = beta1 + p.v1, softmax, s2
    kB<false><<<NBLK, blk, 0, stream>>>(xT, w, s, n2_part, betaT, s_part);
    kR<<<NRED, blk, 0, stream>>>(s_part, s, n2_part);
    // final squash -> out
    k_out<<<NRED, blk, 0, stream>>>(s, n2_part, out);
}

// Round 14
// 94.213 us; speedup vs baseline: 1.4247x; 1.0081x over previous
//
#include <hip/hip_runtime.h>
#include <math.h>

#define NC    10
#define BATCH 256
#define IC    1152
#define LDIM  8
#define OC    16

#define NCH   96
#define CH    (IC/NCH)        // 12 i's per block
#define NBLK  (NC*NCH)        // 960 blocks
#define NTHR  256
#define NTOT  (NC*BATCH*OC)   // 40960
#define NRED  160             // kR blocks / n2 partials
#define KPG   (NCH/4)         // 24 chunks per wave-group in kR

typedef float f32x2 __attribute__((ext_vector_type(2)));

// R8 n-major swizzle (best measured config)
__device__ __forceinline__ int xcd_swizzle(int bid, int nwg) {
    int cpx = nwg >> 3;
    return (bid & 7) * cpx + (bid >> 3);
}

// ---------------------------------------------------------------------------
// K0: transpose x[b][i][l] -> xT[i][b][l]
// ---------------------------------------------------------------------------
__global__ __launch_bounds__(256) void k0_xT(const float* __restrict__ x,
                                             float* __restrict__ xT)
{
    int u = blockIdx.x * 256 + threadIdx.x;       // < 589824
    int i = u >> 9, r = u & 511, b = r >> 1, h = r & 1;
    reinterpret_cast<float4*>(xT)[u] =
        reinterpret_cast<const float4*>(x)[((size_t)b * IC + i) * 2 + h];
}

// ---------------------------------------------------------------------------
// KA: iter-0 s partials (c uniform = 1/256). thread = b.
// ---------------------------------------------------------------------------
__global__ __launch_bounds__(256) void kA(
    const float* __restrict__ xT, const float* __restrict__ w,
    float* __restrict__ s_part)
{
    int wg = xcd_swizzle(blockIdx.x, NBLK);
    int n  = wg / NCH, ch = wg % NCH;
    int i0 = ch * CH;
    int t  = threadIdx.x;            // = b

    f32x2 sp2[8];
#pragma unroll
    for (int j = 0; j < 8; ++j) sp2[j] = (f32x2){0.f, 0.f};

    for (int ii = 0; ii < CH; ++ii) {
        int i = i0 + ii;
        const float4* xp = reinterpret_cast<const float4*>(xT)
                         + ((size_t)i * BATCH + t) * 2;
        float4 xa = xp[0], xb = xp[1];
        float xr[8] = {xa.x, xa.y, xa.z, xa.w, xb.x, xb.y, xb.z, xb.w};
        const f32x2* wp2 = reinterpret_cast<const f32x2*>(
            w + (size_t)__builtin_amdgcn_readfirstlane((n * IC + i) * (LDIM * OC)));
#pragma unroll
        for (int l = 0; l < LDIM; ++l) {
            f32x2 xl = {xr[l], xr[l]};
#pragma unroll
            for (int j = 0; j < 8; ++j)
                sp2[j] += wp2[l * 8 + j] * xl;    // v_pk_fma_f32
        }
    }
    float4* dst = reinterpret_cast<float4*>(s_part)
                + (((size_t)ch * NC + n) * BATCH + t) * 4;
    const float inv = 1.0f / 256.0f;
    dst[0] = make_float4(sp2[0].x*inv, sp2[0].y*inv, sp2[1].x*inv, sp2[1].y*inv);
    dst[1] = make_float4(sp2[2].x*inv, sp2[2].y*inv, sp2[3].x*inv, sp2[3].y*inv);
    dst[2] = make_float4(sp2[4].x*inv, sp2[4].y*inv, sp2[5].x*inv, sp2[5].y*inv);
    dst[3] = make_float4(sp2[6].x*inv, sp2[6].y*inv, sp2[7].x*inv, sp2[7].y*inv);
}

// ---------------------------------------------------------------------------
// KR: 160 blocks. Wave g sums chunks [g*24, g*24+24) as float4 with FOUR
// independent accumulators (fixed tree -> deterministic, ILP-4); LDS combine.
// ---------------------------------------------------------------------------
__global__ __launch_bounds__(256) void kR(const float* __restrict__ s_part,
                                          float* __restrict__ s,
                                          float* __restrict__ n2_part)
{
    __shared__ float4 lds[4][64];
    int t = threadIdx.x, lane = t & 63, g = t >> 6;
    int idx0 = blockIdx.x * 256;
    const float* base = s_part + idx0 + lane * 4;
    float4 a0 = make_float4(0,0,0,0), a1 = a0, a2 = a0, a3 = a0;
    for (int k = 0; k < KPG; k += 4) {
        float4 v0 = *reinterpret_cast<const float4*>(base + (size_t)(g*KPG + k    ) * NTOT);
        float4 v1 = *reinterpret_cast<const float4*>(base + (size_t)(g*KPG + k + 1) * NTOT);
        float4 v2 = *reinterpret_cast<const float4*>(base + (size_t)(g*KPG + k + 2) * NTOT);
        float4 v3 = *reinterpret_cast<const float4*>(base + (size_t)(g*KPG + k + 3) * NTOT);
        a0.x += v0.x; a0.y += v0.y; a0.z += v0.z; a0.w += v0.w;
        a1.x += v1.x; a1.y += v1.y; a1.z += v1.z; a1.w += v1.w;
        a2.x += v2.x; a2.y += v2.y; a2.z += v2.z; a2.w += v2.w;
        a3.x += v3.x; a3.y += v3.y; a3.z += v3.z; a3.w += v3.w;
    }
    float4 a = make_float4((a0.x+a1.x)+(a2.x+a3.x), (a0.y+a1.y)+(a2.y+a3.y),
                           (a0.z+a1.z)+(a2.z+a3.z), (a0.w+a1.w)+(a2.w+a3.w));
    lds[g][lane] = a;
    __syncthreads();
    if (t < 64) {
        float4 s0 = lds[0][t], s1 = lds[1][t], s2 = lds[2][t], s3 = lds[3][t];
        float4 sv = make_float4((s0.x+s1.x)+(s2.x+s3.x), (s0.y+s1.y)+(s2.y+s3.y),
                                (s0.z+s1.z)+(s2.z+s3.z), (s0.w+s1.w)+(s2.w+s3.w));
        *reinterpret_cast<float4*>(s + idx0 + t * 4) = sv;
        float q = sv.x*sv.x + sv.y*sv.y + sv.z*sv.z + sv.w*sv.w;
#pragma unroll
        for (int m = 32; m >= 1; m >>= 1) q += __shfl_xor(q, m, 64);
        if (t == 0) n2_part[blockIdx.x] = q;
    }
}

// ---------------------------------------------------------------------------
// KB: fused routing step, ii-paired, betaT-FREE.
// Linearity: beta_k = p . (v1 + ... + v_{k-1}), so dot against
//   MODE 1: v_eff = s1*sc1           (iter 2)
//   MODE 2: v_eff = s1*sc1 + s2*sc2  (iter 3)
// No beta carrier in memory: -23.6 MB traffic vs R13.
// ---------------------------------------------------------------------------
template<int MODE>
__global__ __launch_bounds__(256) void kB(
    const float* __restrict__ xT, const float* __restrict__ w,
    const float* __restrict__ s1, const float* __restrict__ n2p1,
    const float* __restrict__ s2, const float* __restrict__ n2p2,
    float* __restrict__ s_part)
{
    __shared__ float redA[2][2][4];   // [pair parity][i-slot][wave]
    __shared__ float redW[8];
    int t = threadIdx.x, lane = t & 63, wid = t >> 6;
    int wg = xcd_swizzle(blockIdx.x, NBLK);
    int n  = wg / NCH, ch = wg % NCH;
    int i0 = ch * CH;

    // squash scale(s) from n2 partials (redundant per block, fixed order)
    float q1 = (t < NRED) ? n2p1[t] : 0.f;
    float q2 = (MODE == 2 && t < NRED) ? n2p2[t] : 0.f;
#pragma unroll
    for (int m = 32; m >= 1; m >>= 1) {
        q1 += __shfl_xor(q1, m, 64);
        if (MODE == 2) q2 += __shfl_xor(q2, m, 64);
    }
    if (lane == 0) { redW[wid] = q1; redW[4 + wid] = q2; }
    __syncthreads();
    float n2a = (redW[0] + redW[1]) + (redW[2] + redW[3]);
    float sc1 = sqrtf(n2a) / (1.0f + n2a);

    // v_eff[n,b,:] (packed)
    f32x2 v2[8];
    {
        const f32x2* s1p = reinterpret_cast<const f32x2*>(s1)
                         + ((size_t)n * BATCH + t) * 8;
        f32x2 sv = {sc1, sc1};
#pragma unroll
        for (int j = 0; j < 8; ++j) v2[j] = s1p[j] * sv;
        if (MODE == 2) {
            float n2b = (redW[4] + redW[5]) + (redW[6] + redW[7]);
            float sc2 = sqrtf(n2b) / (1.0f + n2b);
            const f32x2* s2p = reinterpret_cast<const f32x2*>(s2)
                             + ((size_t)n * BATCH + t) * 8;
            f32x2 sw = {sc2, sc2};
#pragma unroll
            for (int j = 0; j < 8; ++j) v2[j] += s2p[j] * sw;
        }
    }

    f32x2 sp2[8];
#pragma unroll
    for (int j = 0; j < 8; ++j) sp2[j] = (f32x2){0.f, 0.f};

    for (int pr = 0; pr < CH / 2; ++pr) {
        int i = i0 + 2 * pr;        // pair {i, i+1}
        const float4* xp = reinterpret_cast<const float4*>(xT)
                         + ((size_t)i * BATCH + t) * 2;
        float4 xa0 = xp[0], xb0 = xp[1];
        float4 xa1 = xp[2 * BATCH], xb1 = xp[2 * BATCH + 1];
        float xr0[8] = {xa0.x, xa0.y, xa0.z, xa0.w, xb0.x, xb0.y, xb0.z, xb0.w};
        float xr1[8] = {xa1.x, xa1.y, xa1.z, xa1.w, xb1.x, xb1.y, xb1.z, xb1.w};
        const f32x2* wp2 = reinterpret_cast<const f32x2*>(
            w + (size_t)__builtin_amdgcn_readfirstlane((n * IC + i) * (LDIM * OC)));

        f32x2 pA[8], pB[8];
#pragma unroll
        for (int j = 0; j < 8; ++j) { pA[j] = (f32x2){0.f,0.f}; pB[j] = (f32x2){0.f,0.f}; }
#pragma unroll
        for (int l = 0; l < LDIM; ++l) {
            f32x2 x0 = {xr0[l], xr0[l]}, x1 = {xr1[l], xr1[l]};
#pragma unroll
            for (int j = 0; j < 8; ++j) {
                pA[j] += wp2[l * 8 + j] * x0;            // i
                pB[j] += wp2[64 + l * 8 + j] * x1;       // i+1 (adjacent w row)
            }
        }

        f32x2 dA = pA[0] * v2[0], dB = pB[0] * v2[0];
#pragma unroll
        for (int j = 1; j < 8; ++j) { dA += pA[j] * v2[j]; dB += pB[j] * v2[j]; }
        float betaA = dA.x + dA.y, betaB = dB.x + dB.y;   // beta_k = p . v_eff

        // in-block softmax over b: two independent chains, ILP-2, ONE barrier
        float eA = __expf(betaA), eB = __expf(betaB);
        float esA = eA, esB = eB;
#pragma unroll
        for (int m = 1; m < 64; m <<= 1) {
            esA += __shfl_xor(esA, m, 64);
            esB += __shfl_xor(esB, m, 64);
        }
        if (lane == 0) { redA[pr & 1][0][wid] = esA; redA[pr & 1][1][wid] = esB; }
        __syncthreads();
        float denA = (redA[pr&1][0][0] + redA[pr&1][0][1])
                   + (redA[pr&1][0][2] + redA[pr&1][0][3]);
        float denB = (redA[pr&1][1][0] + redA[pr&1][1][1])
                   + (redA[pr&1][1][2] + redA[pr&1][1][3]);
        float cA = eA / denA, cB = eB / denB;
        f32x2 cA2 = {cA, cA}, cB2 = {cB, cB};
#pragma unroll
        for (int j = 0; j < 8; ++j) sp2[j] += cA2 * pA[j] + cB2 * pB[j];
    }

    float4* dst = reinterpret_cast<float4*>(s_part)
                + (((size_t)ch * NC + n) * BATCH + t) * 4;
    dst[0] = make_float4(sp2[0].x, sp2[0].y, sp2[1].x, sp2[1].y);
    dst[1] = make_float4(sp2[2].x, sp2[2].y, sp2[3].x, sp2[3].y);
    dst[2] = make_float4(sp2[4].x, sp2[4].y, sp2[5].x, sp2[5].y);
    dst[3] = make_float4(sp2[6].x, sp2[6].y, sp2[7].x, sp2[7].y);
}

// ---------------------------------------------------------------------------
// K_OUT: n2 from partials; out = s * scale
// ---------------------------------------------------------------------------
__global__ __launch_bounds__(256) void k_out(const float* __restrict__ s,
                                             const float* __restrict__ n2_part,
                                             float* __restrict__ out)
{
    __shared__ float redW[4];
    int t = threadIdx.x, lane = t & 63, wid = t >> 6;
    float q = (t < NRED) ? n2_part[t] : 0.f;
#pragma unroll
    for (int m = 32; m >= 1; m >>= 1) q += __shfl_xor(q, m, 64);
    if (lane == 0) redW[wid] = q;
    __syncthreads();
    float n2 = (redW[0] + redW[1]) + (redW[2] + redW[3]);
    float sc = sqrtf(n2) / (1.0f + n2);
    int idx = blockIdx.x * 256 + t;
    out[idx] = s[idx] * sc;
}

// ---------------------------------------------------------------------------
extern "C" void kernel_launch(void* const* d_in, const int* in_sizes, int n_in,
                              void* d_out, int out_size, void* d_ws, size_t ws_size,
                              hipStream_t stream)
{
    const float* x = (const float*)d_in[0];   // [256,1152,8]
    const float* w = (const float*)d_in[1];   // [10,1152,8,16]
    float* out = (float*)d_out;               // 40960 floats
    float* ws  = (float*)d_ws;

    float* xT      = ws;                                  // 2,359,296
    float* s_part  = xT + (size_t)IC * BATCH * LDIM;      // 3,932,160
    float* s1      = s_part + (size_t)NCH * NTOT;         //    40,960
    float* s2      = s1 + NTOT;                           //    40,960
    float* s3      = s2 + NTOT;                           //    40,960
    float* n2p1    = s3 + NTOT;                           //       160
    float* n2p2    = n2p1 + NRED;                         //       160
    float* n2p3    = n2p2 + NRED;                         //       160
    // total ~26 MB of workspace

    dim3 blk(256);

    k0_xT<<<2304, blk, 0, stream>>>(x, xT);
    // iter 1: c uniform
    kA<<<NBLK, blk, 0, stream>>>(xT, w, s_part);
    kR<<<NRED, blk, 0, stream>>>(s_part, s1, n2p1);
    // iter 2: beta1 = p.v1
    kB<1><<<NBLK, blk, 0, stream>>>(xT, w, s1, n2p1, s1, n2p1, s_part);
    kR<<<NRED, blk, 0, stream>>>(s_part, s2, n2p2);
    // iter 3: beta2 = p.(v1+v2) (linearity, no beta carrier)
    kB<2><<<NBLK, blk, 0, stream>>>(xT, w, s1, n2p1, s2, n2p2, s_part);
    kR<<<NRED, blk, 0, stream>>>(s_part, s3, n2p3);
    // final squash -> out
    k_out<<<NRED, blk, 0, stream>>>(s3, n2p3, out);
}